// Round 12
// baseline (2139.220 us; speedup 1.0000x reference)
//
#include <hip/hip_runtime.h>
#include <hip/hip_bf16.h>
#include <math.h>

typedef __hip_bfloat16 bf16;
typedef __attribute__((ext_vector_type(8))) short s8v;   // 8 bf16 (4 VGPRs) MFMA A/B frag
typedef __attribute__((ext_vector_type(4))) float f4v;   // 4 f32 MFMA C/D frag
typedef __attribute__((ext_vector_type(4))) float f4x;   // float4 global load
typedef __attribute__((ext_vector_type(4))) short s4v;   // 4 i16/bf16 (8B)

// Problem dims (fixed for this problem instance)
constexpr int Lc = 3, Dc = 128, Ac = 64, NREL2c = 401;
constexpr int NEc = 600000, NNc = 100000, NQc = 512, NENTc = 50000;
constexpr int NTAUc = 731;
constexpr int HBITS = 18;
constexpr unsigned HSIZE = 1u << HBITS, HMASK = HSIZE - 1u;
constexpr int NBLK = (NNc + 255) / 256;  // 391 scan blocks
constexpr int NTILE = 2;                 // node tiles per node_update block (r11: 4 -> grid 391, occ 16%)

constexpr float SFX = 32767.f, SFXI = 1.f / 32767.f;

// canonical bf16 weight-table offsets (elements), dict order of the 18 float inputs
constexpr int O_RELA = 0;
constexpr int O_WS   = O_RELA + Lc * NREL2c * Dc;
constexpr int O_WR   = O_WS   + Lc * Ac * Dc;
constexpr int O_WQRW = O_WR   + Lc * Ac * Dc;
constexpr int O_WQRB = O_WQRW + Lc * Ac * Dc;
constexpr int O_WTAU = O_WQRB + Lc * Ac;
constexpr int O_WAW  = O_WTAU + Lc * Ac * Dc;
constexpr int O_WAB  = O_WAW  + Lc * Ac;
constexpr int O_WH   = O_WAB  + Lc;
constexpr int O_WT1  = O_WH   + Lc * Dc * Dc;
constexpr int O_BT1  = O_WT1  + Lc * Dc;
constexpr int O_WT2  = O_BT1  + Lc * Dc;
constexpr int O_BT2  = O_WT2  + Lc * Dc;
constexpr int O_WIH  = O_BT2  + Lc * Dc;
constexpr int O_WHH  = O_WIH  + Lc * 3 * Dc * Dc;
constexpr int O_BIH  = O_WHH  + Lc * 3 * Dc * Dc;
constexpr int O_BHH  = O_BIH  + Lc * 3 * Dc;
constexpr int O_WF   = O_BHH  + Lc * 3 * Dc;
constexpr int NWTAB  = O_WF + Dc;

__device__ const int KOFF[19] = {O_RELA, O_WS, O_WR, O_WQRW, O_WQRB, O_WTAU, O_WAW,
                                 O_WAB, O_WH, O_WT1, O_BT1, O_WT2, O_BT2, O_WIH,
                                 O_WHH, O_BIH, O_BHH, O_WF, NWTAB};

struct Ptrs { const void* p[18]; };

__device__ __forceinline__ float b2f(bf16 x) { return __bfloat162float(x); }
__device__ __forceinline__ float bsf(unsigned short u) {
  return __uint_as_float((unsigned)u << 16);
}
__device__ __forceinline__ float sigm(float x) { return 1.f / (1.f + expf(-x)); }
__device__ __forceinline__ float s2f(short s) { return (float)s * SFXI; }
__device__ __forceinline__ short f2s(float v) { return (short)__float2int_rn(v * SFX); }
__device__ __forceinline__ unsigned short f2b(float v) {
  bf16 h = __float2bfloat16(v);
  return *(unsigned short*)&h;
}
__device__ __forceinline__ f4v mfma16(s8v a, s8v b, f4v c) {
  return __builtin_amdgcn_mfma_f32_16x16x32_bf16(a, b, c, 0, 0, 0);
}

// ---------------- dtype detection + weight canonicalization ----------------
__global__ void detect_dtype(const unsigned* __restrict__ w, int* __restrict__ flag) {
  int lane = threadIdx.x & 63;
  int cnt = 0;
  for (int k = lane; k < 256; k += 64) {
    unsigned e = (w[k] >> 7) & 0xffu;
    cnt += (e >= 96u && e <= 140u) ? 1 : 0;
  }
#pragma unroll
  for (int o = 32; o; o >>= 1) cnt += __shfl_xor(cnt, o, 64);
  if (lane == 0) *flag = (cnt >= 128) ? 0 : 1;  // 0 = bf16, 1 = f32
}

__global__ void convert_weights(Ptrs ps, const int* __restrict__ flag,
                                unsigned short* __restrict__ wtab) {
  int idx = blockIdx.x * 256 + threadIdx.x;
  if (idx >= NWTAB) return;
  int b = 0;
  while (idx >= KOFF[b + 1]) ++b;
  int j = idx - KOFF[b];
  unsigned short v;
  if (*flag) v = f2b(((const float*)ps.p[b])[j]);
  else v = ((const unsigned short*)ps.p[b])[j];
  wtab[idx] = v;
}

// ---------------- precompute tables (per layer) ----------------
__global__ void prep_hhau(int l, const bf16* __restrict__ W, float* __restrict__ Hh) {
  int idx = blockIdx.x * 256 + threadIdx.x;
  if (idx >= NTAUc * Dc) return;
  int t = idx >> 7, d = idx & 127;
  float delta = (float)(t - 365);
  Hh[idx] = b2f(W[O_WT1 + l * Dc + d]) * delta + b2f(W[O_BT1 + l * Dc + d]) +
            sinf(b2f(W[O_WT2 + l * Dc + d]) * delta + b2f(W[O_BT2 + l * Dc + d]));
}

__global__ void prep_yr(int l, const bf16* __restrict__ W, float* __restrict__ Yr) {
  int idx = blockIdx.x * 256 + threadIdx.x;
  if (idx >= NREL2c * Ac) return;
  int r = idx >> 6, a = idx & 63;
  const bf16* x = W + O_RELA + (size_t)(l * NREL2c + r) * Dc;
  const bf16* w = W + O_WR + (size_t)(l * Ac + a) * Dc;
  float s = 0.f;
  for (int d = 0; d < Dc; ++d) s = fmaf(b2f(x[d]), b2f(w[d]), s);
  Yr[idx] = s;
}

__global__ void prep_yqr(int l, const bf16* __restrict__ W, const int* __restrict__ q_rel,
                         float* __restrict__ Yqr) {
  int idx = blockIdx.x * 256 + threadIdx.x;
  if (idx >= NQc * Ac) return;
  int q = idx >> 6, a = idx & 63;
  const bf16* x = W + O_RELA + (size_t)(l * NREL2c + q_rel[q]) * Dc;
  const bf16* w = W + O_WQRW + (size_t)(l * Ac + a) * Dc;
  float s = b2f(W[O_WQRB + l * Ac + a]);
  for (int d = 0; d < Dc; ++d) s = fmaf(b2f(x[d]), b2f(w[d]), s);
  Yqr[idx] = s;
}

__global__ void prep_yh(int l, const float* __restrict__ Hh, const bf16* __restrict__ W,
                        float* __restrict__ Yh) {
  int idx = blockIdx.x * 256 + threadIdx.x;
  if (idx >= NTAUc * Ac) return;
  int t = idx >> 6, a = idx & 63;
  const float* x = Hh + (size_t)t * Dc;
  const bf16* w = W + O_WTAU + (size_t)(l * Ac + a) * Dc;
  float s = 0.f;
  for (int d = 0; d < Dc; ++d) s = fmaf(x[d], b2f(w[d]), s);
  Yh[idx] = s;
}

// ---------------- CSR build (exact; per layer) ----------------
__global__ void k_count(const int* __restrict__ e_obj, int base, int* __restrict__ cnt) {
  int e = blockIdx.x * 256 + threadIdx.x;
  if (e < NEc) atomicAdd(&cnt[e_obj[base + e]], 1);
}

__global__ void k_scan1(const int* __restrict__ cnt, int* __restrict__ bsum) {
  __shared__ int s[256];
  int t = threadIdx.x, g = blockIdx.x * 256 + t;
  s[t] = g < NNc ? cnt[g] : 0;
  __syncthreads();
  for (int o = 128; o > 0; o >>= 1) {
    if (t < o) s[t] += s[t + o];
    __syncthreads();
  }
  if (t == 0) bsum[blockIdx.x] = s[0];
}

__global__ void k_scan2(const int* __restrict__ bsum, int* __restrict__ bpre,
                        int* __restrict__ offsets) {
  if (threadIdx.x == 0) {
    int run = 0;
    for (int i = 0; i < NBLK; ++i) { bpre[i] = run; run += bsum[i]; }
    offsets[NNc] = run;  // == NEc
  }
}

__global__ void k_scan3(const int* __restrict__ cnt, const int* __restrict__ bpre,
                        int* __restrict__ offsets, int* __restrict__ cursor) {
  __shared__ int s[256];
  int t = threadIdx.x, g = blockIdx.x * 256 + t;
  int c = g < NNc ? cnt[g] : 0;
  s[t] = c;
  __syncthreads();
  for (int o = 1; o < 256; o <<= 1) {
    int v = (t >= o) ? s[t - o] : 0;
    __syncthreads();
    s[t] += v;
    __syncthreads();
  }
  if (g < NNc) {
    int off = s[t] - c + bpre[blockIdx.x];
    offsets[g] = off;
    cursor[g] = off;
  }
}

__global__ void k_fill(const int* __restrict__ e_obj, int base, int* __restrict__ cursor,
                       int* __restrict__ eidx) {
  int e = blockIdx.x * 256 + threadIdx.x;
  if (e < NEc) {
    int pos = atomicAdd(&cursor[e_obj[base + e]], 1);
    eidx[pos] = e;
  }
}

// ---------------- alpha pass (round-9, unchanged) ----------------
__global__ __launch_bounds__(256, 2) void alpha_kernel(
    int l, const bf16* __restrict__ W, const int* __restrict__ e_sub,
    const int* __restrict__ e_rel, const int* __restrict__ e_ridx,
    const int* __restrict__ e_tau, const int* __restrict__ q_tau,
    const short* __restrict__ state, const float* __restrict__ Yr,
    const float* __restrict__ Yqr, const float* __restrict__ Yh,
    float* __restrict__ alphab, unsigned short* __restrict__ dixb) {
  const int tid = threadIdx.x, lane = tid & 63, w = tid >> 6;
  const int col = lane & 15, quad = lane >> 4;
  const unsigned short* Wu = (const unsigned short*)W;
  s8v Bf[4][4];
  if (l != 0) {
#pragma unroll
    for (int kt = 0; kt < 4; ++kt)
#pragma unroll
      for (int ct = 0; ct < 4; ++ct)
        Bf[kt][ct] =
            *(const s8v*)&Wu[O_WS + (size_t)(l * Ac + ct * 16 + col) * Dc + kt * 32 + quad * 8];
  }
  float wa[4];
#pragma unroll
  for (int ct = 0; ct < 4; ++ct) wa[ct] = b2f(W[O_WAW + l * Ac + ct * 16 + col]);
  const float wb = b2f(W[O_WAB + l]);
  const int base = l * NEc;
  const int gw0 = blockIdx.x * 4 + w, nw = gridDim.x * 4;
  for (int g = gw0; g < NEc / 16; g += nw) {
    int e0 = g * 16;
    int sub16 = e_sub[base + e0 + col];
    int rel16 = e_rel[base + e0 + col];
    int ridx16 = e_ridx[base + e0 + col];
    int et16 = e_tau[base + e0 + col];
    int tq16 = q_tau[ridx16];
    int dix16 = ((et16 >= 0) ? et16 : tq16) - tq16 + 365;
    if (lane < 16) dixb[e0 + lane] = (unsigned short)dix16;
    f4v acc[4];
#pragma unroll
    for (int ct = 0; ct < 4; ++ct) acc[ct] = (f4v)0.f;
    if (l != 0) {
#pragma unroll
      for (int kt = 0; kt < 4; ++kt) {
        const short* sp = &state[(size_t)sub16 * Dc + kt * 32 + quad * 8];
        s8v raw = *(const s8v*)sp;
        s8v a;
#pragma unroll
        for (int j = 0; j < 8; ++j) a[j] = (short)f2b((float)raw[j] * SFXI);
#pragma unroll
        for (int ct = 0; ct < 4; ++ct) acc[ct] = mfma16(a, Bf[kt][ct], acc[ct]);
      }
    }
    float sums[4];
#pragma unroll
    for (int r = 0; r < 4; ++r) {
      int m = quad * 4 + r;
      int rel_m = __shfl(rel16, m, 64);
      int ridx_m = __shfl(ridx16, m, 64);
      int dix_m = __shfl(dix16, m, 64);
      float s = 0.f;
#pragma unroll
      for (int ct = 0; ct < 4; ++ct) {
        int a = ct * 16 + col;
        float v = acc[ct][r] + Yr[rel_m * Ac + a] + Yqr[ridx_m * Ac + a] + Yh[dix_m * Ac + a];
        s = fmaf(fmaxf(v, 0.f), wa[ct], s);
      }
      s += __shfl_xor(s, 1, 64);
      s += __shfl_xor(s, 2, 64);
      s += __shfl_xor(s, 4, 64);
      s += __shfl_xor(s, 8, 64);
      sums[r] = s;
    }
    int rr = col - quad * 4;
    if (rr >= 0 && rr < 4) alphab[e0 + col] = sigm(sums[rr] + wb);
  }
}

// ---------------- gather pass (round-10, unchanged) ----------------
__global__ __launch_bounds__(256) void gather_kernel(
    int l, const bf16* __restrict__ W, const int* __restrict__ offsets,
    const int* __restrict__ eidx, const float* __restrict__ alphab,
    const unsigned short* __restrict__ dixb, const int* __restrict__ e_sub,
    const int* __restrict__ e_rel, const short* __restrict__ state,
    const float* __restrict__ Hh, float* __restrict__ agg) {
  const int lane = threadIdx.x & 63;
  const int gw = (blockIdx.x * 256 + threadIdx.x) >> 6;
  const int nw = (gridDim.x * 256) >> 6;
  const int base = l * NEc;
  for (int i = gw; i < NNc; i += nw) {
    float a0 = 0.f, a1 = 0.f;
    int s = offsets[i], en = offsets[i + 1];
    for (int p = s; p < en; ++p) {
      int e = eidx[p];
      float al = alphab[e];
      int rel = e_rel[base + e];
      int dix = dixb[e];
      float hs0 = 0.f, hs1 = 0.f;
      if (l != 0) {
        int sub = e_sub[base + e];
        hs0 = s2f(state[(size_t)sub * Dc + lane]);
        hs1 = s2f(state[(size_t)sub * Dc + 64 + lane]);
      }
      const bf16* hrp = W + O_RELA + (size_t)(l * NREL2c + rel) * Dc;
      a0 = fmaf(al, hs0 + b2f(hrp[lane]) + Hh[dix * Dc + lane], a0);
      a1 = fmaf(al, hs1 + b2f(hrp[64 + lane]) + Hh[dix * Dc + 64 + lane], a1);
    }
    agg[(size_t)i * Dc + lane] = a0;
    agg[(size_t)i * Dc + 64 + lane] = a1;
  }
}

// ---------------- node kernel v5: gate half (templated hs -> constant reg indexing) --
// ldsH holds EXACT i16 state; h-frags converted i16->bf16 in-register (same values as
// the old staged-bf16 path); h0 read exact from LDS. hout[16] = (1-z)n + z*h0.
template <int HS>
__device__ __forceinline__ void gate_half(
    int l, const unsigned short* __restrict__ Wu, const bf16* __restrict__ W,
    int w, int col, int quad, int kb, int n0,
    unsigned short (&ldsAhi)[64][136], unsigned short (&ldsAlo)[64][136],
    unsigned short (&ldsH)[64][136], float (&hout)[16]) {
  const int jcol = HS * 64 + w * 16 + col;
  const int R = l * 384 + jcol;
  f4v racc[4], zacc[4], niacc[4], nhacc[4];
#pragma unroll
  for (int mt = 0; mt < 4; ++mt) {
    racc[mt] = (f4v)0.f;
    zacc[mt] = (f4v)0.f;
    niacc[mt] = (f4v)0.f;
    nhacc[mt] = (f4v)0.f;
  }
#pragma unroll
  for (int kt = 0; kt < 4; ++kt) {
    int ko = kt * 32 + kb;
    s8v bir = *(const s8v*)&Wu[O_WIH + (size_t)R * Dc + ko];
    s8v biz = *(const s8v*)&Wu[O_WIH + (size_t)(R + 128) * Dc + ko];
    s8v bin = *(const s8v*)&Wu[O_WIH + (size_t)(R + 256) * Dc + ko];
#pragma unroll
    for (int mt = 0; mt < 4; ++mt) {
      s8v xhi = *(const s8v*)&ldsAhi[mt * 16 + col][ko];
      s8v xlo = *(const s8v*)&ldsAlo[mt * 16 + col][ko];
      racc[mt] = mfma16(xhi, bir, racc[mt]);
      racc[mt] = mfma16(xlo, bir, racc[mt]);
      zacc[mt] = mfma16(xhi, biz, zacc[mt]);
      zacc[mt] = mfma16(xlo, biz, zacc[mt]);
      niacc[mt] = mfma16(xhi, bin, niacc[mt]);
      niacc[mt] = mfma16(xlo, bin, niacc[mt]);
    }
    if (l != 0) {
      s8v bhr = *(const s8v*)&Wu[O_WHH + (size_t)R * Dc + ko];
      s8v bhz = *(const s8v*)&Wu[O_WHH + (size_t)(R + 128) * Dc + ko];
      s8v bhn = *(const s8v*)&Wu[O_WHH + (size_t)(R + 256) * Dc + ko];
#pragma unroll
      for (int mt = 0; mt < 4; ++mt) {
        s8v raw = *(const s8v*)&ldsH[mt * 16 + col][ko];
        s8v hf;
#pragma unroll
        for (int j = 0; j < 8; ++j) hf[j] = (short)f2b((float)raw[j] * SFXI);
        racc[mt] = mfma16(hf, bhr, racc[mt]);
        zacc[mt] = mfma16(hf, bhz, zacc[mt]);
        nhacc[mt] = mfma16(hf, bhn, nhacc[mt]);
      }
    }
  }
  float bir_ = b2f(W[O_BIH + R]) + b2f(W[O_BHH + R]);
  float biz_ = b2f(W[O_BIH + R + 128]) + b2f(W[O_BHH + R + 128]);
  float bin_ = b2f(W[O_BIH + R + 256]);
  float bhn_ = b2f(W[O_BHH + R + 256]);
#pragma unroll
  for (int mt = 0; mt < 4; ++mt) {
#pragma unroll
    for (int r_ = 0; r_ < 4; ++r_) {
      float rg = sigm(racc[mt][r_] + bir_);
      float zg = sigm(zacc[mt][r_] + biz_);
      float ng = tanhf(niacc[mt][r_] + bin_ + rg * (nhacc[mt][r_] + bhn_));
      float h0 = (l != 0) ? s2f((short)ldsH[mt * 16 + quad * 4 + r_][jcol]) : 0.f;
      hout[mt * 4 + r_] = (1.f - zg) * ng + zg * h0;
    }
  }
}

// 64-node tile x NTILE, 4 waves. v5: ldsH exact i16; epilogue buffered in regs,
// written via LDS, streamed to state as coalesced 16B/lane nt stores (r11: 64
// scattered 2B nt stores/wave -> WRITE 98MB partial lines + exposed latency).
__global__ __launch_bounds__(256, 3) void node_update(
    int l, const bf16* __restrict__ W, const float* __restrict__ agg,
    short* __restrict__ state) {
  __shared__ __align__(16) unsigned short ldsAhi[64][136];
  __shared__ __align__(16) unsigned short ldsAlo[64][136];
  __shared__ __align__(16) unsigned short ldsH[64][136];  // exact i16 state tile
  const int tid = threadIdx.x;
  const int lane = tid & 63;
  const int w = tid >> 6;
  const int col = lane & 15;
  const int quad = lane >> 4;
  const int kb = quad * 8;
  const unsigned short* Wu = (const unsigned short*)W;

  // Wh B-frags once per block (32 VGPRs)
  s8v whb[2][4];
#pragma unroll
  for (int kt = 0; kt < 4; ++kt) {
    whb[0][kt] = *(const s8v*)&Wu[O_WH + (size_t)(l * Dc + w * 16 + col) * Dc + kt * 32 + kb];
    whb[1][kt] =
        *(const s8v*)&Wu[O_WH + (size_t)(l * Dc + (w + 4) * 16 + col) * Dc + kt * 32 + kb];
  }

#pragma unroll 1
  for (int tile = 0; tile < NTILE; ++tile) {
    const int n0 = (blockIdx.x * NTILE + tile) * 64;
    if (n0 >= NNc) break;
    if (tile) __syncthreads();  // previous tile's LDS reads complete
    // staging: agg split to hi/lo bf16; state raw i16 copy
    for (int e = tid; e < 64 * 32; e += 256) {
      int i = e >> 5, c = (e & 31) * 4;
      int node = n0 + i;
      f4x av = (f4x)0.f;
      if (node < NNc) av = __builtin_nontemporal_load((const f4x*)&agg[(size_t)node * Dc + c]);
      s4v hi4, lo4;
#pragma unroll
      for (int j = 0; j < 4; ++j) {
        unsigned short hi = f2b(av[j]);
        hi4[j] = (short)hi;
        lo4[j] = (short)f2b(av[j] - bsf(hi));
      }
      *(s4v*)&ldsAhi[i][c] = hi4;
      *(s4v*)&ldsAlo[i][c] = lo4;
      if (l != 0) {
        s4v hv4 = (s4v)0;
        if (node < NNc) hv4 = *(const s4v*)&state[(size_t)node * Dc + c];
        *(s4v*)&ldsH[i][c] = hv4;
      }
    }
    __syncthreads();

    // phase 1: x = relu(agg @ Wh^T); wave w -> col-tiles {w, w+4}
    f4v xo[2][4];
#pragma unroll
    for (int c = 0; c < 2; ++c)
#pragma unroll
      for (int mt = 0; mt < 4; ++mt) xo[c][mt] = (f4v)0.f;
#pragma unroll
    for (int kt = 0; kt < 4; ++kt) {
      int ko = kt * 32 + kb;
#pragma unroll
      for (int mt = 0; mt < 4; ++mt) {
        s8v ahi = *(const s8v*)&ldsAhi[mt * 16 + col][ko];
        s8v alo = *(const s8v*)&ldsAlo[mt * 16 + col][ko];
        xo[0][mt] = mfma16(ahi, whb[0][kt], xo[0][mt]);
        xo[0][mt] = mfma16(alo, whb[0][kt], xo[0][mt]);
        xo[1][mt] = mfma16(ahi, whb[1][kt], xo[1][mt]);
        xo[1][mt] = mfma16(alo, whb[1][kt], xo[1][mt]);
      }
    }
    __syncthreads();  // all waves done reading agg planes
#pragma unroll
    for (int c = 0; c < 2; ++c) {
      int t = w + 4 * c;
#pragma unroll
      for (int mt = 0; mt < 4; ++mt) {
#pragma unroll
        for (int r = 0; r < 4; ++r) {
          float x = fmaxf(xo[c][mt][r], 0.f);
          unsigned short hi = f2b(x);
          ldsAhi[mt * 16 + quad * 4 + r][t * 16 + col] = hi;
          ldsAlo[mt * 16 + quad * 4 + r][t * 16 + col] = f2b(x - bsf(hi));
        }
      }
    }
    __syncthreads();

    // phase 2: both gate halves into registers (constant indexing via template)
    float hout0[16], hout1[16];
    gate_half<0>(l, Wu, W, w, col, quad, kb, n0, ldsAhi, ldsAlo, ldsH, hout0);
    gate_half<1>(l, Wu, W, w, col, quad, kb, n0, ldsAhi, ldsAlo, ldsH, hout1);
    __syncthreads();  // all waves done reading x/h planes
    // buffer h' (i16) in ldsAhi, then stream out coalesced
#pragma unroll
    for (int mt = 0; mt < 4; ++mt) {
#pragma unroll
      for (int r_ = 0; r_ < 4; ++r_) {
        int row = mt * 16 + quad * 4 + r_;
        ldsAhi[row][w * 16 + col] = (unsigned short)f2s(hout0[mt * 4 + r_]);
        ldsAhi[row][64 + w * 16 + col] = (unsigned short)f2s(hout1[mt * 4 + r_]);
      }
    }
    __syncthreads();
    for (int e = tid; e < 64 * 16; e += 256) {
      int i = e >> 4, c = (e & 15) * 8;
      int node = n0 + i;
      if (node < NNc) {
        s8v hv = *(const s8v*)&ldsAhi[i][c];
        __builtin_nontemporal_store(hv, (s8v*)&state[(size_t)node * Dc + c]);
      }
    }
  }
}

// ---------------- final score + last-write-wins scatter ----------------
__global__ __launch_bounds__(256) void score_kernel(const short* __restrict__ state,
                                                    const bf16* __restrict__ W,
                                                    float* __restrict__ scores) {
  const int lane = threadIdx.x & 63;
  const int gw = (blockIdx.x * 256 + threadIdx.x) >> 6;
  const int nw = (gridDim.x * 256) >> 6;
  const float w0 = b2f(W[O_WF + lane]), w1 = b2f(W[O_WF + 64 + lane]);
  for (int i = gw; i < NNc; i += nw) {
    float v = s2f(state[(size_t)i * Dc + lane]) * w0 + s2f(state[(size_t)i * Dc + 64 + lane]) * w1;
#pragma unroll
    for (int o = 32; o; o >>= 1) v += __shfl_xor(v, o, 64);
    if (lane == 0) scores[i] = v;
  }
}

__global__ void zero_out(unsigned* __restrict__ out, const int* __restrict__ flag) {
  long words = ((long)NQc * NENTc / 2) * (*flag ? 2 : 1);
  long i = (long)blockIdx.x * 256 + threadIdx.x;
  long stride = (long)gridDim.x * 256;
  for (; i < words; i += stride) out[i] = 0u;
}

__device__ __forceinline__ unsigned hpos(unsigned pos) { return (pos * 2654435761u) >> (32 - HBITS); }

__global__ void scat1(const int* __restrict__ nb, const int* __restrict__ ne,
                      unsigned* __restrict__ hkey, int* __restrict__ hval) {
  int i = blockIdx.x * 256 + threadIdx.x;
  if (i >= NNc) return;
  unsigned pos = (unsigned)(nb[i] * NENTc + ne[i]);
  unsigned key = pos + 1u;
  unsigned h = hpos(pos);
  while (true) {
    unsigned prev = atomicCAS(&hkey[h], 0u, key);
    if (prev == 0u || prev == key) {
      atomicMax(&hval[h], i);
      break;
    }
    h = (h + 1u) & HMASK;
  }
}

__global__ void scat2(const int* __restrict__ nb, const int* __restrict__ ne,
                      const unsigned* __restrict__ hkey, const int* __restrict__ hval,
                      const float* __restrict__ scores, const int* __restrict__ flag,
                      void* __restrict__ out) {
  int i = blockIdx.x * 256 + threadIdx.x;
  if (i >= NNc) return;
  unsigned pos = (unsigned)(nb[i] * NENTc + ne[i]);
  unsigned key = pos + 1u;
  unsigned h = hpos(pos);
  while (true) {
    unsigned k = hkey[h];
    if (k == key) {
      if (hval[h] == i) {
        if (*flag) ((float*)out)[pos] = scores[i];
        else ((bf16*)out)[pos] = __float2bfloat16(scores[i]);
      }
      break;
    }
    if (k == 0u) break;
    h = (h + 1u) & HMASK;
  }
}

// ---------------- launch ----------------
extern "C" void kernel_launch(void* const* d_in, const int* in_sizes, int n_in,
                              void* d_out, int out_size, void* d_ws, size_t ws_size,
                              hipStream_t stream) {
  const int* q_rel = (const int*)d_in[18];
  const int* q_tau = (const int*)d_in[19];
  const int* e_ridx = (const int*)d_in[20];
  const int* e_rel = (const int*)d_in[21];
  const int* e_tau = (const int*)d_in[22];
  const int* e_sub = (const int*)d_in[23];
  const int* e_obj = (const int*)d_in[24];
  const int* n_batch = (const int*)d_in[25];
  const int* n_ent_i = (const int*)d_in[26];

  // ---- workspace: identical 52.6 MB envelope (proven safe) ----
  char* p = (char*)d_ws;
  auto alloc = [&](size_t bytes) {
    void* r = (void*)p;
    p += (bytes + 255) & ~(size_t)255;
    return r;
  };
  int* flag = (int*)alloc(256);
  bf16* wtab = (bf16*)alloc((size_t)NWTAB * 2);        // ~1.2 MB
  short* state = (short*)alloc((size_t)NNc * Dc * 2);  // 25.6 MB i16
  char* big = (char*)alloc((size_t)NNc * Dc * 2);      // 25.6 MB time-shared
  float* Yr = (float*)big;
  float* Yqr = (float*)(big + 102912);
  float* Hh = (float*)(big + 233984);
  float* Yh = (float*)(big + 608256);
  float* alphab = (float*)(big + 800000);
  unsigned short* dixb = (unsigned short*)(big + 3200000);
  int* cnt = (int*)(big + 4400128);
  int* cursor = (int*)(big + 4800384);
  int* offsets = (int*)(big + 5200640);
  int* bsum = (int*)(big + 5600768);
  int* bpre = (int*)(big + 5602560);
  int* eidx = (int*)(big + 5604352);
  float* scores = (float*)big;
  unsigned* hkey = (unsigned*)(big + 400128);
  int* hval = (int*)(big + 400128 + (size_t)HSIZE * 4);

  float* agg = (float*)d_out;  // 51.2 MB scratch during layer loop

  detect_dtype<<<1, 64, 0, stream>>>((const unsigned*)d_in[0], flag);
  Ptrs ps;
  for (int i = 0; i < 18; ++i) ps.p[i] = d_in[i];
  convert_weights<<<(NWTAB + 255) / 256, 256, 0, stream>>>(ps, flag, (unsigned short*)wtab);
  hipMemsetAsync(state, 0, (size_t)NNc * Dc * 2, stream);

  for (int l = 0; l < Lc; ++l) {
    hipMemsetAsync(cnt, 0, (size_t)NNc * 4, stream);
    prep_hhau<<<(NTAUc * Dc + 255) / 256, 256, 0, stream>>>(l, wtab, Hh);
    prep_yr<<<(NREL2c * Ac + 255) / 256, 256, 0, stream>>>(l, wtab, Yr);
    prep_yqr<<<(NQc * Ac + 255) / 256, 256, 0, stream>>>(l, wtab, q_rel, Yqr);
    prep_yh<<<(NTAUc * Ac + 255) / 256, 256, 0, stream>>>(l, Hh, wtab, Yh);
    k_count<<<(NEc + 255) / 256, 256, 0, stream>>>(e_obj, l * NEc, cnt);
    k_scan1<<<NBLK, 256, 0, stream>>>(cnt, bsum);
    k_scan2<<<1, 64, 0, stream>>>(bsum, bpre, offsets);
    k_scan3<<<NBLK, 256, 0, stream>>>(cnt, bpre, offsets, cursor);
    k_fill<<<(NEc + 255) / 256, 256, 0, stream>>>(e_obj, l * NEc, cursor, eidx);
    alpha_kernel<<<2048, 256, 0, stream>>>(l, wtab, e_sub, e_rel, e_ridx, e_tau, q_tau,
                                           state, Yr, Yqr, Yh, alphab, dixb);
    gather_kernel<<<2048, 256, 0, stream>>>(l, wtab, offsets, eidx, alphab, dixb, e_sub,
                                            e_rel, state, Hh, agg);
    node_update<<<(NNc + 64 * NTILE - 1) / (64 * NTILE), 256, 0, stream>>>(l, wtab, agg, state);
  }
  score_kernel<<<1024, 256, 0, stream>>>(state, wtab, scores);
  hipMemsetAsync(hkey, 0, (size_t)HSIZE * 4, stream);
  hipMemsetAsync(hval, 0, (size_t)HSIZE * 4, stream);
  zero_out<<<2048, 256, 0, stream>>>((unsigned*)d_out, flag);
  scat1<<<(NNc + 255) / 256, 256, 0, stream>>>(n_batch, n_ent_i, hkey, hval);
  scat2<<<(NNc + 255) / 256, 256, 0, stream>>>(n_batch, n_ent_i, hkey, hval, scores, flag, d_out);
}

// Round 13
// 1889.331 us; speedup vs baseline: 1.1323x; 1.1323x over previous
//
#include <hip/hip_runtime.h>
#include <hip/hip_bf16.h>
#include <math.h>

typedef __hip_bfloat16 bf16;
typedef __attribute__((ext_vector_type(8))) short s8v;   // 8 bf16 (4 VGPRs) MFMA A/B frag
typedef __attribute__((ext_vector_type(4))) float f4v;   // 4 f32 MFMA C/D frag
typedef __attribute__((ext_vector_type(4))) float f4x;   // float4 global load
typedef __attribute__((ext_vector_type(4))) short s4v;   // 4 i16/bf16 (8B)

// Problem dims (fixed for this problem instance)
constexpr int Lc = 3, Dc = 128, Ac = 64, NREL2c = 401;
constexpr int NEc = 600000, NNc = 100000, NQc = 512, NENTc = 50000;
constexpr int NTAUc = 731;
constexpr int HBITS = 18;
constexpr unsigned HSIZE = 1u << HBITS, HMASK = HSIZE - 1u;
constexpr int NBLK = (NNc + 255) / 256;  // 391 scan blocks
// NTILE=4 -> grid 391: gate-weight set stays L2-resident (r11 FETCH 86 MB);
// NTILE=2 -> grid 782 thrashes it (r12 FETCH 263 MB). Traffic >> occupancy here.
constexpr int NTILE = 4;

constexpr float SFX = 32767.f, SFXI = 1.f / 32767.f;

// canonical bf16 weight-table offsets (elements), dict order of the 18 float inputs
constexpr int O_RELA = 0;
constexpr int O_WS   = O_RELA + Lc * NREL2c * Dc;
constexpr int O_WR   = O_WS   + Lc * Ac * Dc;
constexpr int O_WQRW = O_WR   + Lc * Ac * Dc;
constexpr int O_WQRB = O_WQRW + Lc * Ac * Dc;
constexpr int O_WTAU = O_WQRB + Lc * Ac;
constexpr int O_WAW  = O_WTAU + Lc * Ac * Dc;
constexpr int O_WAB  = O_WAW  + Lc * Ac;
constexpr int O_WH   = O_WAB  + Lc;
constexpr int O_WT1  = O_WH   + Lc * Dc * Dc;
constexpr int O_BT1  = O_WT1  + Lc * Dc;
constexpr int O_WT2  = O_BT1  + Lc * Dc;
constexpr int O_BT2  = O_WT2  + Lc * Dc;
constexpr int O_WIH  = O_BT2  + Lc * Dc;
constexpr int O_WHH  = O_WIH  + Lc * 3 * Dc * Dc;
constexpr int O_BIH  = O_WHH  + Lc * 3 * Dc * Dc;
constexpr int O_BHH  = O_BIH  + Lc * 3 * Dc;
constexpr int O_WF   = O_BHH  + Lc * 3 * Dc;
constexpr int NWTAB  = O_WF + Dc;

__device__ const int KOFF[19] = {O_RELA, O_WS, O_WR, O_WQRW, O_WQRB, O_WTAU, O_WAW,
                                 O_WAB, O_WH, O_WT1, O_BT1, O_WT2, O_BT2, O_WIH,
                                 O_WHH, O_BIH, O_BHH, O_WF, NWTAB};

struct Ptrs { const void* p[18]; };

__device__ __forceinline__ float b2f(bf16 x) { return __bfloat162float(x); }
__device__ __forceinline__ float bsf(unsigned short u) {
  return __uint_as_float((unsigned)u << 16);
}
__device__ __forceinline__ float sigm(float x) { return 1.f / (1.f + expf(-x)); }
__device__ __forceinline__ float s2f(short s) { return (float)s * SFXI; }
__device__ __forceinline__ short f2s(float v) { return (short)__float2int_rn(v * SFX); }
__device__ __forceinline__ unsigned short f2b(float v) {
  bf16 h = __float2bfloat16(v);
  return *(unsigned short*)&h;
}
__device__ __forceinline__ f4v mfma16(s8v a, s8v b, f4v c) {
  return __builtin_amdgcn_mfma_f32_16x16x32_bf16(a, b, c, 0, 0, 0);
}

// ---------------- dtype detection + weight canonicalization ----------------
__global__ void detect_dtype(const unsigned* __restrict__ w, int* __restrict__ flag) {
  int lane = threadIdx.x & 63;
  int cnt = 0;
  for (int k = lane; k < 256; k += 64) {
    unsigned e = (w[k] >> 7) & 0xffu;
    cnt += (e >= 96u && e <= 140u) ? 1 : 0;
  }
#pragma unroll
  for (int o = 32; o; o >>= 1) cnt += __shfl_xor(cnt, o, 64);
  if (lane == 0) *flag = (cnt >= 128) ? 0 : 1;  // 0 = bf16, 1 = f32
}

__global__ void convert_weights(Ptrs ps, const int* __restrict__ flag,
                                unsigned short* __restrict__ wtab) {
  int idx = blockIdx.x * 256 + threadIdx.x;
  if (idx >= NWTAB) return;
  int b = 0;
  while (idx >= KOFF[b + 1]) ++b;
  int j = idx - KOFF[b];
  unsigned short v;
  if (*flag) v = f2b(((const float*)ps.p[b])[j]);
  else v = ((const unsigned short*)ps.p[b])[j];
  wtab[idx] = v;
}

// ---------------- precompute tables (per layer) ----------------
__global__ void prep_hhau(int l, const bf16* __restrict__ W, float* __restrict__ Hh) {
  int idx = blockIdx.x * 256 + threadIdx.x;
  if (idx >= NTAUc * Dc) return;
  int t = idx >> 7, d = idx & 127;
  float delta = (float)(t - 365);
  Hh[idx] = b2f(W[O_WT1 + l * Dc + d]) * delta + b2f(W[O_BT1 + l * Dc + d]) +
            sinf(b2f(W[O_WT2 + l * Dc + d]) * delta + b2f(W[O_BT2 + l * Dc + d]));
}

__global__ void prep_yr(int l, const bf16* __restrict__ W, float* __restrict__ Yr) {
  int idx = blockIdx.x * 256 + threadIdx.x;
  if (idx >= NREL2c * Ac) return;
  int r = idx >> 6, a = idx & 63;
  const bf16* x = W + O_RELA + (size_t)(l * NREL2c + r) * Dc;
  const bf16* w = W + O_WR + (size_t)(l * Ac + a) * Dc;
  float s = 0.f;
  for (int d = 0; d < Dc; ++d) s = fmaf(b2f(x[d]), b2f(w[d]), s);
  Yr[idx] = s;
}

__global__ void prep_yqr(int l, const bf16* __restrict__ W, const int* __restrict__ q_rel,
                         float* __restrict__ Yqr) {
  int idx = blockIdx.x * 256 + threadIdx.x;
  if (idx >= NQc * Ac) return;
  int q = idx >> 6, a = idx & 63;
  const bf16* x = W + O_RELA + (size_t)(l * NREL2c + q_rel[q]) * Dc;
  const bf16* w = W + O_WQRW + (size_t)(l * Ac + a) * Dc;
  float s = b2f(W[O_WQRB + l * Ac + a]);
  for (int d = 0; d < Dc; ++d) s = fmaf(b2f(x[d]), b2f(w[d]), s);
  Yqr[idx] = s;
}

__global__ void prep_yh(int l, const float* __restrict__ Hh, const bf16* __restrict__ W,
                        float* __restrict__ Yh) {
  int idx = blockIdx.x * 256 + threadIdx.x;
  if (idx >= NTAUc * Ac) return;
  int t = idx >> 6, a = idx & 63;
  const float* x = Hh + (size_t)t * Dc;
  const bf16* w = W + O_WTAU + (size_t)(l * Ac + a) * Dc;
  float s = 0.f;
  for (int d = 0; d < Dc; ++d) s = fmaf(x[d], b2f(w[d]), s);
  Yh[idx] = s;
}

// ---------------- CSR build (exact; per layer) ----------------
__global__ void k_count(const int* __restrict__ e_obj, int base, int* __restrict__ cnt) {
  int e = blockIdx.x * 256 + threadIdx.x;
  if (e < NEc) atomicAdd(&cnt[e_obj[base + e]], 1);
}

__global__ void k_scan1(const int* __restrict__ cnt, int* __restrict__ bsum) {
  __shared__ int s[256];
  int t = threadIdx.x, g = blockIdx.x * 256 + t;
  s[t] = g < NNc ? cnt[g] : 0;
  __syncthreads();
  for (int o = 128; o > 0; o >>= 1) {
    if (t < o) s[t] += s[t + o];
    __syncthreads();
  }
  if (t == 0) bsum[blockIdx.x] = s[0];
}

__global__ void k_scan2(const int* __restrict__ bsum, int* __restrict__ bpre,
                        int* __restrict__ offsets) {
  if (threadIdx.x == 0) {
    int run = 0;
    for (int i = 0; i < NBLK; ++i) { bpre[i] = run; run += bsum[i]; }
    offsets[NNc] = run;  // == NEc
  }
}

__global__ void k_scan3(const int* __restrict__ cnt, const int* __restrict__ bpre,
                        int* __restrict__ offsets, int* __restrict__ cursor) {
  __shared__ int s[256];
  int t = threadIdx.x, g = blockIdx.x * 256 + t;
  int c = g < NNc ? cnt[g] : 0;
  s[t] = c;
  __syncthreads();
  for (int o = 1; o < 256; o <<= 1) {
    int v = (t >= o) ? s[t - o] : 0;
    __syncthreads();
    s[t] += v;
    __syncthreads();
  }
  if (g < NNc) {
    int off = s[t] - c + bpre[blockIdx.x];
    offsets[g] = off;
    cursor[g] = off;
  }
}

__global__ void k_fill(const int* __restrict__ e_obj, int base, int* __restrict__ cursor,
                       int* __restrict__ eidx) {
  int e = blockIdx.x * 256 + threadIdx.x;
  if (e < NEc) {
    int pos = atomicAdd(&cursor[e_obj[base + e]], 1);
    eidx[pos] = e;
  }
}

// ---------------- alpha pass (round-9, unchanged) ----------------
__global__ __launch_bounds__(256, 2) void alpha_kernel(
    int l, const bf16* __restrict__ W, const int* __restrict__ e_sub,
    const int* __restrict__ e_rel, const int* __restrict__ e_ridx,
    const int* __restrict__ e_tau, const int* __restrict__ q_tau,
    const short* __restrict__ state, const float* __restrict__ Yr,
    const float* __restrict__ Yqr, const float* __restrict__ Yh,
    float* __restrict__ alphab, unsigned short* __restrict__ dixb) {
  const int tid = threadIdx.x, lane = tid & 63, w = tid >> 6;
  const int col = lane & 15, quad = lane >> 4;
  const unsigned short* Wu = (const unsigned short*)W;
  s8v Bf[4][4];
  if (l != 0) {
#pragma unroll
    for (int kt = 0; kt < 4; ++kt)
#pragma unroll
      for (int ct = 0; ct < 4; ++ct)
        Bf[kt][ct] =
            *(const s8v*)&Wu[O_WS + (size_t)(l * Ac + ct * 16 + col) * Dc + kt * 32 + quad * 8];
  }
  float wa[4];
#pragma unroll
  for (int ct = 0; ct < 4; ++ct) wa[ct] = b2f(W[O_WAW + l * Ac + ct * 16 + col]);
  const float wb = b2f(W[O_WAB + l]);
  const int base = l * NEc;
  const int gw0 = blockIdx.x * 4 + w, nw = gridDim.x * 4;
  for (int g = gw0; g < NEc / 16; g += nw) {
    int e0 = g * 16;
    int sub16 = e_sub[base + e0 + col];
    int rel16 = e_rel[base + e0 + col];
    int ridx16 = e_ridx[base + e0 + col];
    int et16 = e_tau[base + e0 + col];
    int tq16 = q_tau[ridx16];
    int dix16 = ((et16 >= 0) ? et16 : tq16) - tq16 + 365;
    if (lane < 16) dixb[e0 + lane] = (unsigned short)dix16;
    f4v acc[4];
#pragma unroll
    for (int ct = 0; ct < 4; ++ct) acc[ct] = (f4v)0.f;
    if (l != 0) {
#pragma unroll
      for (int kt = 0; kt < 4; ++kt) {
        const short* sp = &state[(size_t)sub16 * Dc + kt * 32 + quad * 8];
        s8v raw = *(const s8v*)sp;
        s8v a;
#pragma unroll
        for (int j = 0; j < 8; ++j) a[j] = (short)f2b((float)raw[j] * SFXI);
#pragma unroll
        for (int ct = 0; ct < 4; ++ct) acc[ct] = mfma16(a, Bf[kt][ct], acc[ct]);
      }
    }
    float sums[4];
#pragma unroll
    for (int r = 0; r < 4; ++r) {
      int m = quad * 4 + r;
      int rel_m = __shfl(rel16, m, 64);
      int ridx_m = __shfl(ridx16, m, 64);
      int dix_m = __shfl(dix16, m, 64);
      float s = 0.f;
#pragma unroll
      for (int ct = 0; ct < 4; ++ct) {
        int a = ct * 16 + col;
        float v = acc[ct][r] + Yr[rel_m * Ac + a] + Yqr[ridx_m * Ac + a] + Yh[dix_m * Ac + a];
        s = fmaf(fmaxf(v, 0.f), wa[ct], s);
      }
      s += __shfl_xor(s, 1, 64);
      s += __shfl_xor(s, 2, 64);
      s += __shfl_xor(s, 4, 64);
      s += __shfl_xor(s, 8, 64);
      sums[r] = s;
    }
    int rr = col - quad * 4;
    if (rr >= 0 && rr < 4) alphab[e0 + col] = sigm(sums[rr] + wb);
  }
}

// ---------------- gather pass (round-10, unchanged) ----------------
__global__ __launch_bounds__(256) void gather_kernel(
    int l, const bf16* __restrict__ W, const int* __restrict__ offsets,
    const int* __restrict__ eidx, const float* __restrict__ alphab,
    const unsigned short* __restrict__ dixb, const int* __restrict__ e_sub,
    const int* __restrict__ e_rel, const short* __restrict__ state,
    const float* __restrict__ Hh, float* __restrict__ agg) {
  const int lane = threadIdx.x & 63;
  const int gw = (blockIdx.x * 256 + threadIdx.x) >> 6;
  const int nw = (gridDim.x * 256) >> 6;
  const int base = l * NEc;
  for (int i = gw; i < NNc; i += nw) {
    float a0 = 0.f, a1 = 0.f;
    int s = offsets[i], en = offsets[i + 1];
    for (int p = s; p < en; ++p) {
      int e = eidx[p];
      float al = alphab[e];
      int rel = e_rel[base + e];
      int dix = dixb[e];
      float hs0 = 0.f, hs1 = 0.f;
      if (l != 0) {
        int sub = e_sub[base + e];
        hs0 = s2f(state[(size_t)sub * Dc + lane]);
        hs1 = s2f(state[(size_t)sub * Dc + 64 + lane]);
      }
      const bf16* hrp = W + O_RELA + (size_t)(l * NREL2c + rel) * Dc;
      a0 = fmaf(al, hs0 + b2f(hrp[lane]) + Hh[dix * Dc + lane], a0);
      a1 = fmaf(al, hs1 + b2f(hrp[64 + lane]) + Hh[dix * Dc + 64 + lane], a1);
    }
    agg[(size_t)i * Dc + lane] = a0;
    agg[(size_t)i * Dc + 64 + lane] = a1;
  }
}

// ---------------- node kernel v6: gate half (templated hs) ----------------
// ldsH holds EXACT i16 state; h-frags converted i16->bf16 in-register; h0 exact
// from LDS. hout[16] = (1-z)n + z*h0.
template <int HS>
__device__ __forceinline__ void gate_half(
    int l, const unsigned short* __restrict__ Wu, const bf16* __restrict__ W,
    int w, int col, int quad, int kb, int n0,
    unsigned short (&ldsAhi)[64][136], unsigned short (&ldsAlo)[64][136],
    unsigned short (&ldsH)[64][136], float (&hout)[16]) {
  const int jcol = HS * 64 + w * 16 + col;
  const int R = l * 384 + jcol;
  f4v racc[4], zacc[4], niacc[4], nhacc[4];
#pragma unroll
  for (int mt = 0; mt < 4; ++mt) {
    racc[mt] = (f4v)0.f;
    zacc[mt] = (f4v)0.f;
    niacc[mt] = (f4v)0.f;
    nhacc[mt] = (f4v)0.f;
  }
#pragma unroll
  for (int kt = 0; kt < 4; ++kt) {
    int ko = kt * 32 + kb;
    s8v bir = *(const s8v*)&Wu[O_WIH + (size_t)R * Dc + ko];
    s8v biz = *(const s8v*)&Wu[O_WIH + (size_t)(R + 128) * Dc + ko];
    s8v bin = *(const s8v*)&Wu[O_WIH + (size_t)(R + 256) * Dc + ko];
#pragma unroll
    for (int mt = 0; mt < 4; ++mt) {
      s8v xhi = *(const s8v*)&ldsAhi[mt * 16 + col][ko];
      s8v xlo = *(const s8v*)&ldsAlo[mt * 16 + col][ko];
      racc[mt] = mfma16(xhi, bir, racc[mt]);
      racc[mt] = mfma16(xlo, bir, racc[mt]);
      zacc[mt] = mfma16(xhi, biz, zacc[mt]);
      zacc[mt] = mfma16(xlo, biz, zacc[mt]);
      niacc[mt] = mfma16(xhi, bin, niacc[mt]);
      niacc[mt] = mfma16(xlo, bin, niacc[mt]);
    }
    if (l != 0) {
      s8v bhr = *(const s8v*)&Wu[O_WHH + (size_t)R * Dc + ko];
      s8v bhz = *(const s8v*)&Wu[O_WHH + (size_t)(R + 128) * Dc + ko];
      s8v bhn = *(const s8v*)&Wu[O_WHH + (size_t)(R + 256) * Dc + ko];
#pragma unroll
      for (int mt = 0; mt < 4; ++mt) {
        s8v raw = *(const s8v*)&ldsH[mt * 16 + col][ko];
        s8v hf;
#pragma unroll
        for (int j = 0; j < 8; ++j) hf[j] = (short)f2b((float)raw[j] * SFXI);
        racc[mt] = mfma16(hf, bhr, racc[mt]);
        zacc[mt] = mfma16(hf, bhz, zacc[mt]);
        nhacc[mt] = mfma16(hf, bhn, nhacc[mt]);
      }
    }
  }
  float bir_ = b2f(W[O_BIH + R]) + b2f(W[O_BHH + R]);
  float biz_ = b2f(W[O_BIH + R + 128]) + b2f(W[O_BHH + R + 128]);
  float bin_ = b2f(W[O_BIH + R + 256]);
  float bhn_ = b2f(W[O_BHH + R + 256]);
#pragma unroll
  for (int mt = 0; mt < 4; ++mt) {
#pragma unroll
    for (int r_ = 0; r_ < 4; ++r_) {
      float rg = sigm(racc[mt][r_] + bir_);
      float zg = sigm(zacc[mt][r_] + biz_);
      float ng = tanhf(niacc[mt][r_] + bin_ + rg * (nhacc[mt][r_] + bhn_));
      float h0 = (l != 0) ? s2f((short)ldsH[mt * 16 + quad * 4 + r_][jcol]) : 0.f;
      hout[mt * 4 + r_] = (1.f - zg) * ng + zg * h0;
    }
  }
}

// 64-node tile x NTILE=4, 4 waves, grid 391 (weights L2-resident).
// Epilogue: buffer h' in LDS, write back with REGULAR cached 16B stores —
// r11's nt 2B scatter gave WRITE 98 MB; r12's nt 16B gave 348 MB (nt defeats
// write-combining). Cached full-line writes -> ~26 MB.
__global__ __launch_bounds__(256, 2) void node_update(
    int l, const bf16* __restrict__ W, const float* __restrict__ agg,
    short* __restrict__ state) {
  __shared__ __align__(16) unsigned short ldsAhi[64][136];
  __shared__ __align__(16) unsigned short ldsAlo[64][136];
  __shared__ __align__(16) unsigned short ldsH[64][136];  // exact i16 state tile
  const int tid = threadIdx.x;
  const int lane = tid & 63;
  const int w = tid >> 6;
  const int col = lane & 15;
  const int quad = lane >> 4;
  const int kb = quad * 8;
  const unsigned short* Wu = (const unsigned short*)W;

  // Wh B-frags once per block (32 VGPRs)
  s8v whb[2][4];
#pragma unroll
  for (int kt = 0; kt < 4; ++kt) {
    whb[0][kt] = *(const s8v*)&Wu[O_WH + (size_t)(l * Dc + w * 16 + col) * Dc + kt * 32 + kb];
    whb[1][kt] =
        *(const s8v*)&Wu[O_WH + (size_t)(l * Dc + (w + 4) * 16 + col) * Dc + kt * 32 + kb];
  }

#pragma unroll 1
  for (int tile = 0; tile < NTILE; ++tile) {
    const int n0 = (blockIdx.x * NTILE + tile) * 64;
    if (n0 >= NNc) break;
    if (tile) __syncthreads();  // previous tile's LDS reads complete
    // staging: agg split to hi/lo bf16 (nt loads: pure stream); state raw i16
    for (int e = tid; e < 64 * 32; e += 256) {
      int i = e >> 5, c = (e & 31) * 4;
      int node = n0 + i;
      f4x av = (f4x)0.f;
      if (node < NNc) av = __builtin_nontemporal_load((const f4x*)&agg[(size_t)node * Dc + c]);
      s4v hi4, lo4;
#pragma unroll
      for (int j = 0; j < 4; ++j) {
        unsigned short hi = f2b(av[j]);
        hi4[j] = (short)hi;
        lo4[j] = (short)f2b(av[j] - bsf(hi));
      }
      *(s4v*)&ldsAhi[i][c] = hi4;
      *(s4v*)&ldsAlo[i][c] = lo4;
      if (l != 0) {
        s4v hv4 = (s4v)0;
        if (node < NNc) hv4 = *(const s4v*)&state[(size_t)node * Dc + c];
        *(s4v*)&ldsH[i][c] = hv4;
      }
    }
    __syncthreads();

    // phase 1: x = relu(agg @ Wh^T); wave w -> col-tiles {w, w+4}
    f4v xo[2][4];
#pragma unroll
    for (int c = 0; c < 2; ++c)
#pragma unroll
      for (int mt = 0; mt < 4; ++mt) xo[c][mt] = (f4v)0.f;
#pragma unroll
    for (int kt = 0; kt < 4; ++kt) {
      int ko = kt * 32 + kb;
#pragma unroll
      for (int mt = 0; mt < 4; ++mt) {
        s8v ahi = *(const s8v*)&ldsAhi[mt * 16 + col][ko];
        s8v alo = *(const s8v*)&ldsAlo[mt * 16 + col][ko];
        xo[0][mt] = mfma16(ahi, whb[0][kt], xo[0][mt]);
        xo[0][mt] = mfma16(alo, whb[0][kt], xo[0][mt]);
        xo[1][mt] = mfma16(ahi, whb[1][kt], xo[1][mt]);
        xo[1][mt] = mfma16(alo, whb[1][kt], xo[1][mt]);
      }
    }
    __syncthreads();  // all waves done reading agg planes
#pragma unroll
    for (int c = 0; c < 2; ++c) {
      int t = w + 4 * c;
#pragma unroll
      for (int mt = 0; mt < 4; ++mt) {
#pragma unroll
        for (int r = 0; r < 4; ++r) {
          float x = fmaxf(xo[c][mt][r], 0.f);
          unsigned short hi = f2b(x);
          ldsAhi[mt * 16 + quad * 4 + r][t * 16 + col] = hi;
          ldsAlo[mt * 16 + quad * 4 + r][t * 16 + col] = f2b(x - bsf(hi));
        }
      }
    }
    __syncthreads();

    // phase 2: both gate halves into registers (constant indexing via template)
    float hout0[16], hout1[16];
    gate_half<0>(l, Wu, W, w, col, quad, kb, n0, ldsAhi, ldsAlo, ldsH, hout0);
    gate_half<1>(l, Wu, W, w, col, quad, kb, n0, ldsAhi, ldsAlo, ldsH, hout1);
    __syncthreads();  // all waves done reading x/h planes
    // buffer h' (i16) in ldsAhi, then stream out coalesced (cached stores)
#pragma unroll
    for (int mt = 0; mt < 4; ++mt) {
#pragma unroll
      for (int r_ = 0; r_ < 4; ++r_) {
        int row = mt * 16 + quad * 4 + r_;
        ldsAhi[row][w * 16 + col] = (unsigned short)f2s(hout0[mt * 4 + r_]);
        ldsAhi[row][64 + w * 16 + col] = (unsigned short)f2s(hout1[mt * 4 + r_]);
      }
    }
    __syncthreads();
    for (int e = tid; e < 64 * 16; e += 256) {
      int i = e >> 4, c = (e & 15) * 8;
      int node = n0 + i;
      if (node < NNc) {
        s8v hv = *(const s8v*)&ldsAhi[i][c];
        *(s8v*)&state[(size_t)node * Dc + c] = hv;  // cached: full-line write-back
      }
    }
  }
}

// ---------------- final score + last-write-wins scatter ----------------
__global__ __launch_bounds__(256) void score_kernel(const short* __restrict__ state,
                                                    const bf16* __restrict__ W,
                                                    float* __restrict__ scores) {
  const int lane = threadIdx.x & 63;
  const int gw = (blockIdx.x * 256 + threadIdx.x) >> 6;
  const int nw = (gridDim.x * 256) >> 6;
  const float w0 = b2f(W[O_WF + lane]), w1 = b2f(W[O_WF + 64 + lane]);
  for (int i = gw; i < NNc; i += nw) {
    float v = s2f(state[(size_t)i * Dc + lane]) * w0 + s2f(state[(size_t)i * Dc + 64 + lane]) * w1;
#pragma unroll
    for (int o = 32; o; o >>= 1) v += __shfl_xor(v, o, 64);
    if (lane == 0) scores[i] = v;
  }
}

__global__ void zero_out(unsigned* __restrict__ out, const int* __restrict__ flag) {
  long words = ((long)NQc * NENTc / 2) * (*flag ? 2 : 1);
  long i = (long)blockIdx.x * 256 + threadIdx.x;
  long stride = (long)gridDim.x * 256;
  for (; i < words; i += stride) out[i] = 0u;
}

__device__ __forceinline__ unsigned hpos(unsigned pos) { return (pos * 2654435761u) >> (32 - HBITS); }

__global__ void scat1(const int* __restrict__ nb, const int* __restrict__ ne,
                      unsigned* __restrict__ hkey, int* __restrict__ hval) {
  int i = blockIdx.x * 256 + threadIdx.x;
  if (i >= NNc) return;
  unsigned pos = (unsigned)(nb[i] * NENTc + ne[i]);
  unsigned key = pos + 1u;
  unsigned h = hpos(pos);
  while (true) {
    unsigned prev = atomicCAS(&hkey[h], 0u, key);
    if (prev == 0u || prev == key) {
      atomicMax(&hval[h], i);
      break;
    }
    h = (h + 1u) & HMASK;
  }
}

__global__ void scat2(const int* __restrict__ nb, const int* __restrict__ ne,
                      const unsigned* __restrict__ hkey, const int* __restrict__ hval,
                      const float* __restrict__ scores, const int* __restrict__ flag,
                      void* __restrict__ out) {
  int i = blockIdx.x * 256 + threadIdx.x;
  if (i >= NNc) return;
  unsigned pos = (unsigned)(nb[i] * NENTc + ne[i]);
  unsigned key = pos + 1u;
  unsigned h = hpos(pos);
  while (true) {
    unsigned k = hkey[h];
    if (k == key) {
      if (hval[h] == i) {
        if (*flag) ((float*)out)[pos] = scores[i];
        else ((bf16*)out)[pos] = __float2bfloat16(scores[i]);
      }
      break;
    }
    if (k == 0u) break;
    h = (h + 1u) & HMASK;
  }
}

// ---------------- launch ----------------
extern "C" void kernel_launch(void* const* d_in, const int* in_sizes, int n_in,
                              void* d_out, int out_size, void* d_ws, size_t ws_size,
                              hipStream_t stream) {
  const int* q_rel = (const int*)d_in[18];
  const int* q_tau = (const int*)d_in[19];
  const int* e_ridx = (const int*)d_in[20];
  const int* e_rel = (const int*)d_in[21];
  const int* e_tau = (const int*)d_in[22];
  const int* e_sub = (const int*)d_in[23];
  const int* e_obj = (const int*)d_in[24];
  const int* n_batch = (const int*)d_in[25];
  const int* n_ent_i = (const int*)d_in[26];

  // ---- workspace: identical 52.6 MB envelope (proven safe) ----
  char* p = (char*)d_ws;
  auto alloc = [&](size_t bytes) {
    void* r = (void*)p;
    p += (bytes + 255) & ~(size_t)255;
    return r;
  };
  int* flag = (int*)alloc(256);
  bf16* wtab = (bf16*)alloc((size_t)NWTAB * 2);        // ~1.2 MB
  short* state = (short*)alloc((size_t)NNc * Dc * 2);  // 25.6 MB i16
  char* big = (char*)alloc((size_t)NNc * Dc * 2);      // 25.6 MB time-shared
  float* Yr = (float*)big;
  float* Yqr = (float*)(big + 102912);
  float* Hh = (float*)(big + 233984);
  float* Yh = (float*)(big + 608256);
  float* alphab = (float*)(big + 800000);
  unsigned short* dixb = (unsigned short*)(big + 3200000);
  int* cnt = (int*)(big + 4400128);
  int* cursor = (int*)(big + 4800384);
  int* offsets = (int*)(big + 5200640);
  int* bsum = (int*)(big + 5600768);
  int* bpre = (int*)(big + 5602560);
  int* eidx = (int*)(big + 5604352);
  float* scores = (float*)big;
  unsigned* hkey = (unsigned*)(big + 400128);
  int* hval = (int*)(big + 400128 + (size_t)HSIZE * 4);

  float* agg = (float*)d_out;  // 51.2 MB scratch during layer loop

  detect_dtype<<<1, 64, 0, stream>>>((const unsigned*)d_in[0], flag);
  Ptrs ps;
  for (int i = 0; i < 18; ++i) ps.p[i] = d_in[i];
  convert_weights<<<(NWTAB + 255) / 256, 256, 0, stream>>>(ps, flag, (unsigned short*)wtab);
  hipMemsetAsync(state, 0, (size_t)NNc * Dc * 2, stream);

  for (int l = 0; l < Lc; ++l) {
    hipMemsetAsync(cnt, 0, (size_t)NNc * 4, stream);
    prep_hhau<<<(NTAUc * Dc + 255) / 256, 256, 0, stream>>>(l, wtab, Hh);
    prep_yr<<<(NREL2c * Ac + 255) / 256, 256, 0, stream>>>(l, wtab, Yr);
    prep_yqr<<<(NQc * Ac + 255) / 256, 256, 0, stream>>>(l, wtab, q_rel, Yqr);
    prep_yh<<<(NTAUc * Ac + 255) / 256, 256, 0, stream>>>(l, Hh, wtab, Yh);
    k_count<<<(NEc + 255) / 256, 256, 0, stream>>>(e_obj, l * NEc, cnt);
    k_scan1<<<NBLK, 256, 0, stream>>>(cnt, bsum);
    k_scan2<<<1, 64, 0, stream>>>(bsum, bpre, offsets);
    k_scan3<<<NBLK, 256, 0, stream>>>(cnt, bpre, offsets, cursor);
    k_fill<<<(NEc + 255) / 256, 256, 0, stream>>>(e_obj, l * NEc, cursor, eidx);
    alpha_kernel<<<2048, 256, 0, stream>>>(l, wtab, e_sub, e_rel, e_ridx, e_tau, q_tau,
                                           state, Yr, Yqr, Yh, alphab, dixb);
    gather_kernel<<<2048, 256, 0, stream>>>(l, wtab, offsets, eidx, alphab, dixb, e_sub,
                                            e_rel, state, Hh, agg);
    node_update<<<(NNc + 64 * NTILE - 1) / (64 * NTILE), 256, 0, stream>>>(l, wtab, agg, state);
  }
  score_kernel<<<1024, 256, 0, stream>>>(state, wtab, scores);
  hipMemsetAsync(hkey, 0, (size_t)HSIZE * 4, stream);
  hipMemsetAsync(hval, 0, (size_t)HSIZE * 4, stream);
  zero_out<<<2048, 256, 0, stream>>>((unsigned*)d_out, flag);
  scat1<<<(NNc + 255) / 256, 256, 0, stream>>>(n_batch, n_ent_i, hkey, hval);
  scat2<<<(NNc + 255) / 256, 256, 0, stream>>>(n_batch, n_ent_i, hkey, hval, scores, flag, d_out);
}